// Round 4
// baseline (623.270 us; speedup 1.0000x reference)
//
#include <hip/hip_runtime.h>

typedef __attribute__((ext_vector_type(8))) short short8;
typedef __attribute__((ext_vector_type(8))) unsigned short ushort8_t;
typedef __attribute__((ext_vector_type(4))) float floatx4;
typedef __attribute__((ext_vector_type(2))) _Float16 half2_t;
typedef __attribute__((ext_vector_type(4))) _Float16 half4;
typedef __attribute__((ext_vector_type(8))) _Float16 half8;

#define B_ 4
#define S_ 2048
#define D_ 1024
#define H_ 16
#define DK_ 64
#define BS_ (B_ * S_)   // 8192

union V8u { half8 v8; half4 v4[2]; };
union H16 { _Float16 h; unsigned short u; };

typedef const __attribute__((address_space(1))) void* gvp;
typedef __attribute__((address_space(3))) void* lvp;

// ---------- helpers ----------
static __device__ __forceinline__ unsigned short f2bf(float f) {
  union { float f; unsigned int u; } x; x.f = f;
  unsigned int r = x.u + 0x7fffu + ((x.u >> 16) & 1u);   // RNE
  return (unsigned short)(r >> 16);
}

static __device__ __forceinline__ half2_t pk_f16(float a, float b) {
  return __builtin_bit_cast(half2_t, __builtin_amdgcn_cvt_pkrtz(a, b));
}

// ---------- cast fp32 -> bf16, 4 elems/thread ----------
__global__ void cast_kernel(const float* __restrict__ in, unsigned short* __restrict__ out, int n4) {
  int i = blockIdx.x * blockDim.x + threadIdx.x;
  if (i < n4) {
    float4 v = ((const float4*)in)[i];
    ushort4 o;
    o.x = f2bf(v.x); o.y = f2bf(v.y); o.z = f2bf(v.z); o.w = f2bf(v.w);
    ((ushort4*)out)[i] = o;
  }
}

// fused 4-weight cast: blockIdx.y selects which weight
__global__ void cast4_kernel(const float* __restrict__ a, const float* __restrict__ b,
                             const float* __restrict__ c, const float* __restrict__ d,
                             unsigned short* __restrict__ oa, unsigned short* __restrict__ ob,
                             unsigned short* __restrict__ oc, unsigned short* __restrict__ od, int n4) {
  int i = blockIdx.x * blockDim.x + threadIdx.x;
  int w = blockIdx.y;
  const float* src = (w == 0) ? a : (w == 1) ? b : (w == 2) ? c : d;
  unsigned short* dst = (w == 0) ? oa : (w == 1) ? ob : (w == 2) ? oc : od;
  if (i < n4) {
    float4 v = ((const float4*)src)[i];
    ushort4 o;
    o.x = f2bf(v.x); o.y = f2bf(v.y); o.z = f2bf(v.z); o.w = f2bf(v.w);
    ((ushort4*)dst)[i] = o;
  }
}

// ---------- mask int32 -> bitmask (bit=1 means keep) ----------
__global__ void pack_mask(const int* __restrict__ mask, unsigned long long* __restrict__ bits) {
  int i = blockIdx.x * blockDim.x + threadIdx.x;
  unsigned long long m = __ballot(mask[i] != 0);
  if ((threadIdx.x & 63) == 0) bits[i >> 6] = m;
}

// ---------- V [B,H,S,64] (f16) -> Vt [B,H,64,S] (f16), k-permuted per 64-block ----------
__global__ void transpose_v(const unsigned short* __restrict__ Vh, unsigned short* __restrict__ Vt) {
  __shared__ unsigned short T[64][72];
  int bh = blockIdx.y;
  int s0 = blockIdx.x * 64;
  int tid = threadIdx.x;
  int r = tid >> 3, c = (tid & 7) * 8;
  const unsigned short* src = Vh + ((size_t)bh * S_ + s0) * DK_;
#pragma unroll
  for (int p = 0; p < 2; ++p)
    *(uint4*)(&T[r + p * 32][c]) = *(const uint4*)(src + (size_t)(r + p * 32) * DK_ + c);
  __syncthreads();
  unsigned short* dst = Vt + (size_t)bh * DK_ * S_;
#pragma unroll
  for (int p = 0; p < 2; ++p) {
    int d = r + p * 32;
    ushort8_t o;
#pragma unroll
    for (int i = 0; i < 8; ++i) {
      int pos = c + i;
      int th = pos >> 5, rem = pos & 31;
      int q4 = rem >> 3, rem2 = rem & 7;
      int t = th * 2 + (rem2 >> 2), j = rem2 & 3;
      int k = t * 16 + q4 * 4 + j;
      o[i] = T[k][d];
    }
    *(ushort8_t*)(dst + (size_t)d * S_ + s0 + c) = o;
  }
}

// ---------- GEMM: Y = scale*(X(MxK) * W(NxK)^T + bias), m97-style global_load_lds staging ----------
// mode 0: bf16 out, head layout [B,H,S,64]; mode 2: f16 out head layout; mode 1: fp32 out row-major
__global__ __launch_bounds__(256) void gemm_bt(
    const unsigned short* __restrict__ X,
    const unsigned short* __restrict__ W,
    const float* __restrict__ bias,
    void* __restrict__ Y, int M, int N, int K, float scale, int mode)
{
  __shared__ unsigned short As[128 * 64];
  __shared__ unsigned short Bs[128 * 64];
  int tid = threadIdx.x;
  int wave = tid >> 6, lane = tid & 63, quad = lane >> 4, li = lane & 15;
  int wm = wave >> 1, wn = wave & 1;
  int bm = blockIdx.y, bn = blockIdx.x;

  // staging: wave w stages rows [w*32, w*32+32); call j covers 8 rows; lane -> (row=lane/8, colgrp=lane%8)
  int srow = lane >> 3, scol = (lane & 7) * 8;
  const unsigned short* gA = X + (size_t)(bm * 128 + wave * 32 + srow) * K + scol;
  const unsigned short* gB = W + (size_t)(bn * 128 + wave * 32 + srow) * K + scol;
  unsigned short* ldsA = &As[wave * 2048];
  unsigned short* ldsB = &Bs[wave * 2048];

  floatx4 acc[4][4] = {};

  for (int k0 = 0; k0 < K; k0 += 64) {
    __syncthreads();
#pragma unroll
    for (int j = 0; j < 4; ++j) {
      __builtin_amdgcn_global_load_lds((gvp)(gA + (size_t)(j * 8) * K + k0), (lvp)(ldsA + j * 512), 16, 0, 0);
      __builtin_amdgcn_global_load_lds((gvp)(gB + (size_t)(j * 8) * K + k0), (lvp)(ldsB + j * 512), 16, 0, 0);
    }
    __syncthreads();   // drains vmcnt -> staged data visible
#pragma unroll
    for (int s2 = 0; s2 < 2; ++s2) {
      short8 af[4], bf[4];
#pragma unroll
      for (int t = 0; t < 4; ++t) {
        af[t] = *(const short8*)(&As[(wm * 64 + t * 16 + li) * 64 + s2 * 32 + quad * 8]);
        bf[t] = *(const short8*)(&Bs[(wn * 64 + t * 16 + li) * 64 + s2 * 32 + quad * 8]);
      }
#pragma unroll
      for (int mt = 0; mt < 4; ++mt)
#pragma unroll
        for (int nt = 0; nt < 4; ++nt)
          acc[mt][nt] = __builtin_amdgcn_mfma_f32_16x16x32_bf16(af[mt], bf[nt], acc[mt][nt], 0, 0, 0);
    }
  }

#pragma unroll
  for (int nt = 0; nt < 4; ++nt) {
    int n = bn * 128 + wn * 64 + nt * 16 + li;
    float bv = bias[n];
#pragma unroll
    for (int mt = 0; mt < 4; ++mt) {
#pragma unroll
      for (int r = 0; r < 4; ++r) {
        int m = bm * 128 + wm * 64 + mt * 16 + quad * 4 + r;
        float v = (acc[mt][nt][r] + bv) * scale;
        if (mode == 1) {
          ((float*)Y)[(size_t)m * N + n] = v;
        } else {
          int b = m >> 11, s = m & 2047, h = n >> 6, dk = n & 63;
          size_t idx = (((size_t)(b * H_ + h)) * S_ + s) * DK_ + dk;
          if (mode == 0) {
            ((unsigned short*)Y)[idx] = f2bf(v);
          } else {
            H16 hv; hv.h = (_Float16)v;
            ((unsigned short*)Y)[idx] = hv.u;
          }
        }
      }
    }
  }
}

// ---------- flash attention, register double-buffered k-tiles ----------
__global__ __launch_bounds__(256) void attn_kernel(
    const unsigned short* __restrict__ Qh,
    const unsigned short* __restrict__ Kh,
    const _Float16* __restrict__ Vt,
    const unsigned long long* __restrict__ mbits,
    unsigned short* __restrict__ attnb)
{
  int tid = threadIdx.x;
  int wave = tid >> 6, lane = tid & 63, quad = lane >> 4, li = lane & 15;

  int blk = blockIdx.x;
  int xcd = blk & 7, slot = blk >> 3;
  int bh = xcd * 8 + (slot >> 4);
  int qb = slot & 15;
  int b = bh >> 4, h = bh & 15;
  int qbase = qb * 128 + wave * 32;
  const size_t hq = (size_t)bh * S_ * DK_;

  short8 aQ[2][2];
#pragma unroll
  for (int qs = 0; qs < 2; ++qs)
#pragma unroll
    for (int s2 = 0; s2 < 2; ++s2)
      aQ[qs][s2] = *(const short8*)(Qh + hq + (size_t)(qbase + qs * 16 + li) * DK_ + s2 * 32 + quad * 8);

  floatx4 o[2][4] = {};
  float l[2] = {0.f, 0.f};

  const unsigned long long* mrow = mbits + ((size_t)b * S_ + qbase + li) * (S_ / 64);
  const _Float16* vb0 = Vt + ((size_t)bh * 64 + li) * S_ + quad * 8;
  const unsigned short* kb0 = Kh + hq + (size_t)li * DK_ + quad * 8;

  // double-buffered tile registers
  short8 bK[2][4][2];
  V8u bV[2][4][2];
  unsigned long long mw0[2], mw1[2];

  auto load_tile = [&](int buf, int k0) {
    int kw = k0 >> 6;
#pragma unroll
    for (int t = 0; t < 4; ++t)
#pragma unroll
      for (int s2 = 0; s2 < 2; ++s2)
        bK[buf][t][s2] = *(const short8*)(kb0 + (size_t)(k0 + t * 16) * DK_ + s2 * 32);
#pragma unroll
    for (int dt = 0; dt < 4; ++dt)
#pragma unroll
      for (int tp = 0; tp < 2; ++tp)
        bV[buf][dt][tp].v8 = *(const half8*)(vb0 + (size_t)(dt * 16) * S_ + k0 + tp * 32);
    mw0[buf] = mrow[kw];
    mw1[buf] = mrow[16 * (S_ / 64) + kw];
  };

  auto compute_tile = [&](int buf) {
    unsigned long long sh0 = mw0[buf] >> (quad * 4);
    unsigned long long sh1 = mw1[buf] >> (quad * 4);

    floatx4 sc[4][2] = {};
#pragma unroll
    for (int s2 = 0; s2 < 2; ++s2)
#pragma unroll
      for (int t = 0; t < 4; ++t)
#pragma unroll
        for (int qs = 0; qs < 2; ++qs)
          sc[t][qs] = __builtin_amdgcn_mfma_f32_16x16x32_bf16(bK[buf][t][s2], aQ[qs][s2], sc[t][qs], 0, 0, 0);

    half4 aP[4][2];
#pragma unroll
    for (int t = 0; t < 4; ++t)
#pragma unroll
      for (int qs = 0; qs < 2; ++qs) {
        unsigned nb = (unsigned)(((qs ? sh1 : sh0) >> (t * 16)) & 15u);
        float p0 = (nb & 1u)        ? exp2f(sc[t][qs][0]) : 0.f;
        float p1 = ((nb >> 1) & 1u) ? exp2f(sc[t][qs][1]) : 0.f;
        float p2 = ((nb >> 2) & 1u) ? exp2f(sc[t][qs][2]) : 0.f;
        float p3 = ((nb >> 3) & 1u) ? exp2f(sc[t][qs][3]) : 0.f;
        l[qs] += (p0 + p1) + (p2 + p3);
        half2_t plo = pk_f16(p0, p1);
        half2_t phi = pk_f16(p2, p3);
        aP[t][qs] = __builtin_shufflevector(plo, phi, 0, 1, 2, 3);
      }

#pragma unroll
    for (int t = 0; t < 4; ++t)
#pragma unroll
      for (int qs = 0; qs < 2; ++qs)
#pragma unroll
        for (int dt = 0; dt < 4; ++dt)
          o[qs][dt] = __builtin_amdgcn_mfma_f32_16x16x16f16(aP[t][qs], bV[buf][dt][t >> 1].v4[t & 1], o[qs][dt], 0, 0, 0);
  };

  load_tile(0, 0);
  for (int k0 = 0; k0 < S_; k0 += 128) {
    load_tile(1, k0 + 64);          // prefetch next tile while computing current
    compute_tile(0);
    if (k0 + 128 < S_) load_tile(0, k0 + 128);
    compute_tile(1);
  }

  float inv[2];
#pragma unroll
  for (int qs = 0; qs < 2; ++qs) {
    float lf = l[qs];
    lf += __shfl_xor(lf, 16, 64);
    lf += __shfl_xor(lf, 32, 64);
    inv[qs] = 1.0f / lf;
  }
#pragma unroll
  for (int qs = 0; qs < 2; ++qs)
#pragma unroll
    for (int r = 0; r < 4; ++r) {
      float ir = __shfl(inv[qs], quad * 4 + r, 64);
      size_t row = (size_t)b * S_ + qbase + qs * 16 + quad * 4 + r;
#pragma unroll
      for (int dt = 0; dt < 4; ++dt)
        attnb[row * D_ + h * DK_ + dt * 16 + li] = f2bf(o[qs][dt][r] * ir);
    }
}

// ---------- host ----------
extern "C" void kernel_launch(void* const* d_in, const int* in_sizes, int n_in,
                              void* d_out, int out_size, void* d_ws, size_t ws_size,
                              hipStream_t stream) {
  const float* query = (const float*)d_in[0];
  const float* key   = (const float*)d_in[1];
  const float* value = (const float*)d_in[2];
  const int*   mask  = (const int*)d_in[3];
  const float* Wq = (const float*)d_in[4];
  const float* bq = (const float*)d_in[5];
  const float* Wk = (const float*)d_in[6];
  const float* bk = (const float*)d_in[7];
  const float* Wv = (const float*)d_in[8];
  const float* bv = (const float*)d_in[9];
  const float* Wo = (const float*)d_in[10];
  const float* bo = (const float*)d_in[11];
  float* out = (float*)d_out;

  char* ws = (char*)d_ws;
  size_t off = 0;
  auto alloc = [&](size_t bytes) -> void* {
    void* p = ws + off;
    off += (bytes + 255) & ~(size_t)255;
    return p;
  };
  unsigned short* Xb    = (unsigned short*)alloc((size_t)BS_ * D_ * 2);
  unsigned short* Wqb   = (unsigned short*)alloc((size_t)D_ * D_ * 2);
  unsigned short* Wkb   = (unsigned short*)alloc((size_t)D_ * D_ * 2);
  unsigned short* Wvb   = (unsigned short*)alloc((size_t)D_ * D_ * 2);
  unsigned short* Wob   = (unsigned short*)alloc((size_t)D_ * D_ * 2);
  unsigned short* Qh    = (unsigned short*)alloc((size_t)BS_ * D_ * 2);
  unsigned short* Kh    = (unsigned short*)alloc((size_t)BS_ * D_ * 2);
  unsigned short* Vh    = (unsigned short*)alloc((size_t)BS_ * D_ * 2);  // f16 bits
  unsigned short* Vt    = (unsigned short*)alloc((size_t)BS_ * D_ * 2);  // f16 bits
  unsigned short* attnb = (unsigned short*)alloc((size_t)BS_ * D_ * 2);
  unsigned long long* mbits = (unsigned long long*)alloc((size_t)B_ * S_ * (S_ / 64) * 8);

  const float SC = 0.18033688011112042f;  // (1/8) * log2(e), folded into Q

  pack_mask<<<(B_ * S_ * S_) / 256, 256, 0, stream>>>(mask, mbits);

  int wn4 = D_ * D_ / 4;
  cast4_kernel<<<dim3(wn4 / 256, 4), 256, 0, stream>>>(Wq, Wk, Wv, Wo, Wqb, Wkb, Wvb, Wob, wn4);

  int xn4 = BS_ * D_ / 4;
  dim3 gg(D_ / 128, BS_ / 128), gb(256);

  cast_kernel<<<xn4 / 256, 256, 0, stream>>>(query, Xb, xn4);
  gemm_bt<<<gg, gb, 0, stream>>>(Xb, Wqb, bq, Qh, BS_, D_, D_, SC, 0);
  cast_kernel<<<xn4 / 256, 256, 0, stream>>>(key, Xb, xn4);
  gemm_bt<<<gg, gb, 0, stream>>>(Xb, Wkb, bk, Kh, BS_, D_, D_, 1.0f, 0);
  cast_kernel<<<xn4 / 256, 256, 0, stream>>>(value, Xb, xn4);
  gemm_bt<<<gg, gb, 0, stream>>>(Xb, Wvb, bv, Vh, BS_, D_, D_, 1.0f, 2);
  transpose_v<<<dim3(S_ / 64, B_ * H_), 256, 0, stream>>>(Vh, Vt);

  attn_kernel<<<dim3(8 * 8 * 16), 256, 0, stream>>>(Qh, Kh, (const _Float16*)Vt, mbits, attnb);

  gemm_bt<<<gg, gb, 0, stream>>>(attnb, Wob, bo, out, BS_, D_, D_, 1.0f, 1);
}

// Round 5
// 503.417 us; speedup vs baseline: 1.2381x; 1.2381x over previous
//
#include <hip/hip_runtime.h>

typedef __attribute__((ext_vector_type(8))) short short8;
typedef __attribute__((ext_vector_type(8))) unsigned short ushort8_t;
typedef __attribute__((ext_vector_type(4))) float floatx4;
typedef __attribute__((ext_vector_type(2))) _Float16 half2_t;
typedef __attribute__((ext_vector_type(4))) _Float16 half4;
typedef __attribute__((ext_vector_type(8))) _Float16 half8;

#define B_ 4
#define S_ 2048
#define D_ 1024
#define H_ 16
#define DK_ 64
#define BS_ (B_ * S_)   // 8192

union V8u { half8 v8; half4 v4[2]; };
union H16 { _Float16 h; unsigned short u; };

typedef const __attribute__((address_space(1))) void* gvp;
typedef __attribute__((address_space(3))) void* lvp;

// ---------- helpers ----------
static __device__ __forceinline__ unsigned short f2bf(float f) {
  union { float f; unsigned int u; } x; x.f = f;
  unsigned int r = x.u + 0x7fffu + ((x.u >> 16) & 1u);   // RNE
  return (unsigned short)(r >> 16);
}

static __device__ __forceinline__ half2_t pk_f16(float a, float b) {
  return __builtin_bit_cast(half2_t, __builtin_amdgcn_cvt_pkrtz(a, b));
}

// ---------- cast fp32 -> bf16, 4 elems/thread ----------
__global__ void cast_kernel(const float* __restrict__ in, unsigned short* __restrict__ out, int n4) {
  int i = blockIdx.x * blockDim.x + threadIdx.x;
  if (i < n4) {
    float4 v = ((const float4*)in)[i];
    ushort4 o;
    o.x = f2bf(v.x); o.y = f2bf(v.y); o.z = f2bf(v.z); o.w = f2bf(v.w);
    ((ushort4*)out)[i] = o;
  }
}

// fused 4-weight cast
__global__ void cast4_kernel(const float* __restrict__ a, const float* __restrict__ b,
                             const float* __restrict__ c, const float* __restrict__ d,
                             unsigned short* __restrict__ oa, unsigned short* __restrict__ ob,
                             unsigned short* __restrict__ oc, unsigned short* __restrict__ od, int n4) {
  int i = blockIdx.x * blockDim.x + threadIdx.x;
  int w = blockIdx.y;
  const float* src = (w == 0) ? a : (w == 1) ? b : (w == 2) ? c : d;
  unsigned short* dst = (w == 0) ? oa : (w == 1) ? ob : (w == 2) ? oc : od;
  if (i < n4) {
    float4 v = ((const float4*)src)[i];
    ushort4 o;
    o.x = f2bf(v.x); o.y = f2bf(v.y); o.z = f2bf(v.z); o.w = f2bf(v.w);
    ((ushort4*)dst)[i] = o;
  }
}

// ---------- mask int32 -> bitmask (bit=1 means keep) ----------
__global__ void pack_mask(const int* __restrict__ mask, unsigned long long* __restrict__ bits) {
  int i = blockIdx.x * blockDim.x + threadIdx.x;
  unsigned long long m = __ballot(mask[i] != 0);
  if ((threadIdx.x & 63) == 0) bits[i >> 6] = m;
}

// ---------- V [B,H,S,64] (f16) -> Vt [B,H,64,S] (f16), k-permuted per 64-block ----------
__global__ void transpose_v(const unsigned short* __restrict__ Vh, unsigned short* __restrict__ Vt) {
  __shared__ unsigned short T[64][72];
  int bh = blockIdx.y;
  int s0 = blockIdx.x * 64;
  int tid = threadIdx.x;
  int r = tid >> 3, c = (tid & 7) * 8;
  const unsigned short* src = Vh + ((size_t)bh * S_ + s0) * DK_;
#pragma unroll
  for (int p = 0; p < 2; ++p)
    *(uint4*)(&T[r + p * 32][c]) = *(const uint4*)(src + (size_t)(r + p * 32) * DK_ + c);
  __syncthreads();
  unsigned short* dst = Vt + (size_t)bh * DK_ * S_;
#pragma unroll
  for (int p = 0; p < 2; ++p) {
    int d = r + p * 32;
    ushort8_t o;
#pragma unroll
    for (int i = 0; i < 8; ++i) {
      int pos = c + i;
      int th = pos >> 5, rem = pos & 31;
      int q4 = rem >> 3, rem2 = rem & 7;
      int t = th * 2 + (rem2 >> 2), j = rem2 & 3;
      int k = t * 16 + q4 * 4 + j;
      o[i] = T[k][d];
    }
    *(ushort8_t*)(dst + (size_t)d * S_ + s0 + c) = o;
  }
}

// ---------- GEMM: Y = scale*(X(MxK) * W(NxK)^T + bias), global_load_lds + XOR-swizzled LDS ----------
// LDS slot s at row r holds global colgrp (s ^ (r&7)); read side applies same XOR.
__global__ __launch_bounds__(256) void gemm_bt(
    const unsigned short* __restrict__ X,
    const unsigned short* __restrict__ W,
    const float* __restrict__ bias,
    void* __restrict__ Y, int M, int N, int K, float scale, int mode)
{
  __shared__ __align__(16) unsigned short As[128 * 64];
  __shared__ __align__(16) unsigned short Bs[128 * 64];
  int tid = threadIdx.x;
  int wave = tid >> 6, lane = tid & 63, quad = lane >> 4, li = lane & 15;
  int wm = wave >> 1, wn = wave & 1;
  int bm = blockIdx.y, bn = blockIdx.x;

  // staging: wave w stages rows [w*32, w*32+32); call j covers 8 rows
  int srow = lane >> 3;
  int scol = ((lane & 7) ^ srow) * 8;     // XOR swizzle on global side
  const unsigned short* gA = X + (size_t)(bm * 128 + wave * 32 + srow) * K + scol;
  const unsigned short* gB = W + (size_t)(bn * 128 + wave * 32 + srow) * K + scol;
  unsigned short* ldsA = &As[wave * 2048];
  unsigned short* ldsB = &Bs[wave * 2048];

  floatx4 acc[4][4] = {};

  for (int k0 = 0; k0 < K; k0 += 64) {
    __syncthreads();
#pragma unroll
    for (int j = 0; j < 4; ++j) {
      __builtin_amdgcn_global_load_lds((gvp)(gA + (size_t)(j * 8) * K + k0), (lvp)(ldsA + j * 512), 16, 0, 0);
      __builtin_amdgcn_global_load_lds((gvp)(gB + (size_t)(j * 8) * K + k0), (lvp)(ldsB + j * 512), 16, 0, 0);
    }
    __syncthreads();
#pragma unroll
    for (int s2 = 0; s2 < 2; ++s2) {
      short8 af[4], bf[4];
#pragma unroll
      for (int t = 0; t < 4; ++t) {
        int ra = wm * 64 + t * 16 + li;
        int rb = wn * 64 + t * 16 + li;
        int slot = ((s2 * 4 + quad) ^ (li & 7)) * 8;
        af[t] = *(const short8*)(&As[ra * 64 + slot]);
        bf[t] = *(const short8*)(&Bs[rb * 64 + slot]);
      }
#pragma unroll
      for (int mt = 0; mt < 4; ++mt)
#pragma unroll
        for (int nt = 0; nt < 4; ++nt)
          acc[mt][nt] = __builtin_amdgcn_mfma_f32_16x16x32_bf16(af[mt], bf[nt], acc[mt][nt], 0, 0, 0);
    }
  }

#pragma unroll
  for (int nt = 0; nt < 4; ++nt) {
    int n = bn * 128 + wn * 64 + nt * 16 + li;
    float bv = bias[n];
#pragma unroll
    for (int mt = 0; mt < 4; ++mt) {
#pragma unroll
      for (int r = 0; r < 4; ++r) {
        int m = bm * 128 + wm * 64 + mt * 16 + quad * 4 + r;
        float v = (acc[mt][nt][r] + bv) * scale;
        if (mode == 1) {
          ((float*)Y)[(size_t)m * N + n] = v;
        } else {
          int b = m >> 11, s = m & 2047, h = n >> 6, dk = n & 63;
          size_t idx = (((size_t)(b * H_ + h)) * S_ + s) * DK_ + dk;
          if (mode == 0) {
            ((unsigned short*)Y)[idx] = f2bf(v);
          } else {
            H16 hv; hv.h = (_Float16)v;
            ((unsigned short*)Y)[idx] = hv.u;
          }
        }
      }
    }
  }
}

// ---------- flash attention: block-shared LDS K/V tiles, swizzled, transposed-score softmax ----------
__global__ __launch_bounds__(256) void attn_kernel(
    const unsigned short* __restrict__ Qh,
    const unsigned short* __restrict__ Kh,
    const _Float16* __restrict__ Vt,
    const unsigned long long* __restrict__ mbits,
    unsigned short* __restrict__ attnb)
{
  __shared__ __align__(16) unsigned short Ks[64 * 64];
  __shared__ __align__(16) unsigned short Vs[64 * 64];

  int tid = threadIdx.x;
  int wave = tid >> 6, lane = tid & 63, quad = lane >> 4, li = lane & 15;

  int blk = blockIdx.x;
  int xcd = blk & 7, slot7 = blk >> 3;
  int bh = xcd * 8 + (slot7 >> 4);
  int qb = slot7 & 15;
  int b = bh >> 4, h = bh & 15;
  int qbase = qb * 128 + wave * 32;
  const size_t hq = (size_t)bh * S_ * DK_;

  // Q fragments (B-operand of S^T mfma), loaded once from global
  short8 aQ[2][2];
#pragma unroll
  for (int qs = 0; qs < 2; ++qs)
#pragma unroll
    for (int s2 = 0; s2 < 2; ++s2)
      aQ[qs][s2] = *(const short8*)(Qh + hq + (size_t)(qbase + qs * 16 + li) * DK_ + s2 * 32 + quad * 8);

  floatx4 o[2][4] = {};
  float l[2] = {0.f, 0.f};

  const unsigned long long* mrow = mbits + ((size_t)b * S_ + qbase + li) * (S_ / 64);

  // staging addresses: wave w covers rows w*16..w*16+15; call j covers 8 rows
  int srow = lane >> 3;
  int scol = ((lane & 7) ^ srow) * 8;     // XOR swizzle on global side
  const unsigned short* gK = Kh + hq + (size_t)(wave * 16 + srow) * DK_ + scol;
  const _Float16* gV = Vt + ((size_t)bh * 64 + wave * 16 + srow) * S_ + scol;
  unsigned short* ldsK = &Ks[(wave * 16) * 64];
  unsigned short* ldsV = &Vs[(wave * 16) * 64];

  for (int k0 = 0; k0 < S_; k0 += 64) {
    int kw = k0 >> 6;
    __syncthreads();   // all waves done reading previous tile
#pragma unroll
    for (int j = 0; j < 2; ++j) {
      __builtin_amdgcn_global_load_lds((gvp)(gK + (size_t)(k0 + j * 8) * DK_), (lvp)(ldsK + j * 512), 16, 0, 0);
      __builtin_amdgcn_global_load_lds((gvp)(gV + (size_t)(j * 8) * S_ + k0), (lvp)(ldsV + j * 512), 16, 0, 0);
    }
    unsigned long long mw0 = mrow[kw];
    unsigned long long mw1 = mrow[16 * (S_ / 64) + kw];
    __syncthreads();   // staged data visible

    // K fragments from LDS (unswizzle)
    short8 bK[4][2];
#pragma unroll
    for (int t = 0; t < 4; ++t)
#pragma unroll
      for (int s2 = 0; s2 < 2; ++s2)
        bK[t][s2] = *(const short8*)(&Ks[(t * 16 + li) * 64 + (((s2 * 4 + quad) ^ (li & 7)) * 8)]);

    // scores transposed: lane holds S[q=li][k = k0 + t*16 + quad*4 + r]
    floatx4 sc[4][2] = {};
#pragma unroll
    for (int s2 = 0; s2 < 2; ++s2)
#pragma unroll
      for (int t = 0; t < 4; ++t)
#pragma unroll
        for (int qs = 0; qs < 2; ++qs)
          sc[t][qs] = __builtin_amdgcn_mfma_f32_16x16x32_bf16(bK[t][s2], aQ[qs][s2], sc[t][qs], 0, 0, 0);

    unsigned long long sh0 = mw0 >> (quad * 4);
    unsigned long long sh1 = mw1 >> (quad * 4);

    // softmax without max-subtraction (exp2-domain scores): P = mask ? exp2(s) : 0
    half4 aP[4][2];
#pragma unroll
    for (int t = 0; t < 4; ++t)
#pragma unroll
      for (int qs = 0; qs < 2; ++qs) {
        unsigned nb = (unsigned)(((qs ? sh1 : sh0) >> (t * 16)) & 15u);
        float p0 = (nb & 1u)        ? exp2f(sc[t][qs][0]) : 0.f;
        float p1 = ((nb >> 1) & 1u) ? exp2f(sc[t][qs][1]) : 0.f;
        float p2 = ((nb >> 2) & 1u) ? exp2f(sc[t][qs][2]) : 0.f;
        float p3 = ((nb >> 3) & 1u) ? exp2f(sc[t][qs][3]) : 0.f;
        l[qs] += (p0 + p1) + (p2 + p3);
        half2_t plo = pk_f16(p0, p1);
        half2_t phi = pk_f16(p2, p3);
        aP[t][qs] = __builtin_shufflevector(plo, phi, 0, 1, 2, 3);
      }

    // V fragments from LDS (unswizzle)
    V8u vv[4][2];
#pragma unroll
    for (int dt = 0; dt < 4; ++dt)
#pragma unroll
      for (int tp = 0; tp < 2; ++tp)
        vv[dt][tp].v8 = *(const half8*)((const _Float16*)&Vs[(dt * 16 + li) * 64 + (((tp * 4 + quad) ^ (li & 7)) * 8)]);

    // PV
#pragma unroll
    for (int t = 0; t < 4; ++t)
#pragma unroll
      for (int qs = 0; qs < 2; ++qs)
#pragma unroll
        for (int dt = 0; dt < 4; ++dt)
          o[qs][dt] = __builtin_amdgcn_mfma_f32_16x16x16f16(aP[t][qs], vv[dt][t >> 1].v4[t & 1], o[qs][dt], 0, 0, 0);
  }

  float inv[2];
#pragma unroll
  for (int qs = 0; qs < 2; ++qs) {
    float lf = l[qs];
    lf += __shfl_xor(lf, 16, 64);
    lf += __shfl_xor(lf, 32, 64);
    inv[qs] = 1.0f / lf;
  }
#pragma unroll
  for (int qs = 0; qs < 2; ++qs)
#pragma unroll
    for (int r = 0; r < 4; ++r) {
      float ir = __shfl(inv[qs], quad * 4 + r, 64);
      size_t row = (size_t)b * S_ + qbase + qs * 16 + quad * 4 + r;
#pragma unroll
      for (int dt = 0; dt < 4; ++dt)
        attnb[row * D_ + h * DK_ + dt * 16 + li] = f2bf(o[qs][dt][r] * ir);
    }
}

// ---------- host ----------
extern "C" void kernel_launch(void* const* d_in, const int* in_sizes, int n_in,
                              void* d_out, int out_size, void* d_ws, size_t ws_size,
                              hipStream_t stream) {
  const float* query = (const float*)d_in[0];
  const float* key   = (const float*)d_in[1];
  const float* value = (const float*)d_in[2];
  const int*   mask  = (const int*)d_in[3];
  const float* Wq = (const float*)d_in[4];
  const float* bq = (const float*)d_in[5];
  const float* Wk = (const float*)d_in[6];
  const float* bk = (const float*)d_in[7];
  const float* Wv = (const float*)d_in[8];
  const float* bv = (const float*)d_in[9];
  const float* Wo = (const float*)d_in[10];
  const float* bo = (const float*)d_in[11];
  float* out = (float*)d_out;

  char* ws = (char*)d_ws;
  size_t off = 0;
  auto alloc = [&](size_t bytes) -> void* {
    void* p = ws + off;
    off += (bytes + 255) & ~(size_t)255;
    return p;
  };
  unsigned short* Xb    = (unsigned short*)alloc((size_t)BS_ * D_ * 2);
  unsigned short* Wqb   = (unsigned short*)alloc((size_t)D_ * D_ * 2);
  unsigned short* Wkb   = (unsigned short*)alloc((size_t)D_ * D_ * 2);
  unsigned short* Wvb   = (unsigned short*)alloc((size_t)D_ * D_ * 2);
  unsigned short* Wob   = (unsigned short*)alloc((size_t)D_ * D_ * 2);
  unsigned short* Qh    = (unsigned short*)alloc((size_t)BS_ * D_ * 2);
  unsigned short* Kh    = (unsigned short*)alloc((size_t)BS_ * D_ * 2);
  unsigned short* Vh    = (unsigned short*)alloc((size_t)BS_ * D_ * 2);  // f16 bits
  unsigned short* Vt    = (unsigned short*)alloc((size_t)BS_ * D_ * 2);  // f16 bits
  unsigned short* attnb = (unsigned short*)alloc((size_t)BS_ * D_ * 2);
  unsigned long long* mbits = (unsigned long long*)alloc((size_t)B_ * S_ * (S_ / 64) * 8);

  const float SC = 0.18033688011112042f;  // (1/8) * log2(e), folded into Q

  pack_mask<<<(B_ * S_ * S_) / 256, 256, 0, stream>>>(mask, mbits);

  int wn4 = D_ * D_ / 4;
  cast4_kernel<<<dim3(wn4 / 256, 4), 256, 0, stream>>>(Wq, Wk, Wv, Wo, Wqb, Wkb, Wvb, Wob, wn4);

  int xn4 = BS_ * D_ / 4;
  dim3 gg(D_ / 128, BS_ / 128), gb(256);

  cast_kernel<<<xn4 / 256, 256, 0, stream>>>(query, Xb, xn4);
  gemm_bt<<<gg, gb, 0, stream>>>(Xb, Wqb, bq, Qh, BS_, D_, D_, SC, 0);
  cast_kernel<<<xn4 / 256, 256, 0, stream>>>(key, Xb, xn4);
  gemm_bt<<<gg, gb, 0, stream>>>(Xb, Wkb, bk, Kh, BS_, D_, D_, 1.0f, 0);
  cast_kernel<<<xn4 / 256, 256, 0, stream>>>(value, Xb, xn4);
  gemm_bt<<<gg, gb, 0, stream>>>(Xb, Wvb, bv, Vh, BS_, D_, D_, 1.0f, 2);
  transpose_v<<<dim3(S_ / 64, B_ * H_), 256, 0, stream>>>(Vh, Vt);

  attn_kernel<<<dim3(8 * 8 * 16), 256, 0, stream>>>(Qh, Kh, (const _Float16*)Vt, mbits, attnb);

  gemm_bt<<<gg, gb, 0, stream>>>(attnb, Wob, bo, out, BS_, D_, D_, 1.0f, 1);
}

// Round 6
// 503.252 us; speedup vs baseline: 1.2385x; 1.0003x over previous
//
#include <hip/hip_runtime.h>

typedef __attribute__((ext_vector_type(8))) short short8;
typedef __attribute__((ext_vector_type(8))) unsigned short ushort8_t;
typedef __attribute__((ext_vector_type(4))) float floatx4;
typedef __attribute__((ext_vector_type(2))) _Float16 half2_t;
typedef __attribute__((ext_vector_type(4))) _Float16 half4;
typedef __attribute__((ext_vector_type(8))) _Float16 half8;

#define B_ 4
#define S_ 2048
#define D_ 1024
#define H_ 16
#define DK_ 64
#define BS_ (B_ * S_)   // 8192

union V8u { half8 v8; half4 v4[2]; };
union H16 { _Float16 h; unsigned short u; };

typedef const __attribute__((address_space(1))) void* gvp;
typedef __attribute__((address_space(3))) void* lvp;

// ---------- helpers ----------
static __device__ __forceinline__ unsigned short f2bf(float f) {
  union { float f; unsigned int u; } x; x.f = f;
  unsigned int r = x.u + 0x7fffu + ((x.u >> 16) & 1u);   // RNE
  return (unsigned short)(r >> 16);
}

static __device__ __forceinline__ half2_t pk_f16(float a, float b) {
  return __builtin_bit_cast(half2_t, __builtin_amdgcn_cvt_pkrtz(a, b));
}

// ---------- fused input casts (q/k/v) ----------
__global__ void cast3_kernel(const float* __restrict__ a, const float* __restrict__ b,
                             const float* __restrict__ c,
                             unsigned short* __restrict__ oa, unsigned short* __restrict__ ob,
                             unsigned short* __restrict__ oc, int n4) {
  int i = blockIdx.x * blockDim.x + threadIdx.x;
  int w = blockIdx.y;
  const float* src = (w == 0) ? a : (w == 1) ? b : c;
  unsigned short* dst = (w == 0) ? oa : (w == 1) ? ob : oc;
  if (i < n4) {
    float4 v = ((const float4*)src)[i];
    ushort4 o;
    o.x = f2bf(v.x); o.y = f2bf(v.y); o.z = f2bf(v.z); o.w = f2bf(v.w);
    ((ushort4*)dst)[i] = o;
  }
}

// fused 4-weight cast
__global__ void cast4_kernel(const float* __restrict__ a, const float* __restrict__ b,
                             const float* __restrict__ c, const float* __restrict__ d,
                             unsigned short* __restrict__ oa, unsigned short* __restrict__ ob,
                             unsigned short* __restrict__ oc, unsigned short* __restrict__ od, int n4) {
  int i = blockIdx.x * blockDim.x + threadIdx.x;
  int w = blockIdx.y;
  const float* src = (w == 0) ? a : (w == 1) ? b : (w == 2) ? c : d;
  unsigned short* dst = (w == 0) ? oa : (w == 1) ? ob : (w == 2) ? oc : od;
  if (i < n4) {
    float4 v = ((const float4*)src)[i];
    ushort4 o;
    o.x = f2bf(v.x); o.y = f2bf(v.y); o.z = f2bf(v.z); o.w = f2bf(v.w);
    ((ushort4*)dst)[i] = o;
  }
}

// ---------- mask int32 -> bitmask (bit=1 means keep) ----------
__global__ void pack_mask(const int* __restrict__ mask, unsigned long long* __restrict__ bits) {
  int i = blockIdx.x * blockDim.x + threadIdx.x;
  unsigned long long m = __ballot(mask[i] != 0);
  if ((threadIdx.x & 63) == 0) bits[i >> 6] = m;
}

// ---------- V [B,H,S,64] (f16) -> Vt [B,H,64,S] (f16), k-permuted per 64-block ----------
__global__ void transpose_v(const unsigned short* __restrict__ Vh, unsigned short* __restrict__ Vt) {
  __shared__ unsigned short T[64][72];
  int bh = blockIdx.y;
  int s0 = blockIdx.x * 64;
  int tid = threadIdx.x;
  int r = tid >> 3, c = (tid & 7) * 8;
  const unsigned short* src = Vh + ((size_t)bh * S_ + s0) * DK_;
#pragma unroll
  for (int p = 0; p < 2; ++p)
    *(uint4*)(&T[r + p * 32][c]) = *(const uint4*)(src + (size_t)(r + p * 32) * DK_ + c);
  __syncthreads();
  unsigned short* dst = Vt + (size_t)bh * DK_ * S_;
#pragma unroll
  for (int p = 0; p < 2; ++p) {
    int d = r + p * 32;
    ushort8_t o;
#pragma unroll
    for (int i = 0; i < 8; ++i) {
      int pos = c + i;
      int th = pos >> 5, rem = pos & 31;
      int q4 = rem >> 3, rem2 = rem & 7;
      int t = th * 2 + (rem2 >> 2), j = rem2 & 3;
      int k = t * 16 + q4 * 4 + j;
      o[i] = T[k][d];
    }
    *(ushort8_t*)(dst + (size_t)d * S_ + s0 + c) = o;
  }
}

// ---------- pipelined GEMM core: Y = scale*(X(Mx1024) * W(1024x1024)^T + bias) ----------
// Double-buffered LDS; one barrier per K-tile; prefetch issued right after barrier.
// mode 0: bf16 out head layout; mode 2: f16 out head layout; mode 1: fp32 out row-major.
__device__ __forceinline__ void gemm_core(
    const unsigned short* __restrict__ X, const unsigned short* __restrict__ W,
    const float* __restrict__ bias, void* __restrict__ Y,
    float scale, int mode, int bm, int bn,
    unsigned short* As, unsigned short* Bs)
{
  constexpr int K = D_, N = D_;
  int tid = threadIdx.x;
  int wave = tid >> 6, lane = tid & 63, quad = lane >> 4, li = lane & 15;
  int wm = wave >> 1, wn = wave & 1;
  int srow = lane >> 3;
  int scol = ((lane & 7) ^ srow) * 8;   // XOR swizzle on global side
  const unsigned short* gA = X + (size_t)(bm * 128 + wave * 32 + srow) * K + scol;
  const unsigned short* gB = W + (size_t)(bn * 128 + wave * 32 + srow) * K + scol;

  auto stage = [&](int buf, int k0) {
#pragma unroll
    for (int j = 0; j < 4; ++j) {
      __builtin_amdgcn_global_load_lds((gvp)(gA + (size_t)(j * 8) * K + k0),
          (lvp)(As + buf * 8192 + wave * 2048 + j * 512), 16, 0, 0);
      __builtin_amdgcn_global_load_lds((gvp)(gB + (size_t)(j * 8) * K + k0),
          (lvp)(Bs + buf * 8192 + wave * 2048 + j * 512), 16, 0, 0);
    }
  };

  floatx4 acc[4][4] = {};
  stage(0, 0);
  constexpr int NK = K / 64;
  for (int i = 0; i < NK; ++i) {
    int buf = i & 1;
    __syncthreads();                       // buf data valid; prev prefetch already landed
    if (i + 1 < NK) stage(buf ^ 1, (i + 1) * 64);   // prefetch next tile (hidden behind compute)
    short8 af[2][4], bf[2][4];
#pragma unroll
    for (int s2 = 0; s2 < 2; ++s2)
#pragma unroll
      for (int t = 0; t < 4; ++t) {
        int slot = ((s2 * 4 + quad) ^ (li & 7)) * 8;
        af[s2][t] = *(const short8*)(&As[buf * 8192 + (wm * 64 + t * 16 + li) * 64 + slot]);
        bf[s2][t] = *(const short8*)(&Bs[buf * 8192 + (wn * 64 + t * 16 + li) * 64 + slot]);
      }
#pragma unroll
    for (int s2 = 0; s2 < 2; ++s2)
#pragma unroll
      for (int mt = 0; mt < 4; ++mt)
#pragma unroll
        for (int nt = 0; nt < 4; ++nt)
          acc[mt][nt] = __builtin_amdgcn_mfma_f32_16x16x32_bf16(af[s2][mt], bf[s2][nt], acc[mt][nt], 0, 0, 0);
  }

#pragma unroll
  for (int nt = 0; nt < 4; ++nt) {
    int n = bn * 128 + wn * 64 + nt * 16 + li;
    float bv = bias[n];
#pragma unroll
    for (int mt = 0; mt < 4; ++mt) {
#pragma unroll
      for (int r = 0; r < 4; ++r) {
        int m = bm * 128 + wm * 64 + mt * 16 + quad * 4 + r;
        float v = (acc[mt][nt][r] + bv) * scale;
        if (mode == 1) {
          ((float*)Y)[(size_t)m * N + n] = v;
        } else {
          int b = m >> 11, s = m & 2047, h = n >> 6, dk = n & 63;
          size_t idx = (((size_t)(b * H_ + h)) * S_ + s) * DK_ + dk;
          if (mode == 0) {
            ((unsigned short*)Y)[idx] = f2bf(v);
          } else {
            H16 hv; hv.h = (_Float16)v;
            ((unsigned short*)Y)[idx] = hv.u;
          }
        }
      }
    }
  }
}

__global__ __launch_bounds__(256) void gemm_qkv(
    const unsigned short* __restrict__ Xq, const unsigned short* __restrict__ Xk,
    const unsigned short* __restrict__ Xv,
    const unsigned short* __restrict__ Wq, const unsigned short* __restrict__ Wk,
    const unsigned short* __restrict__ Wv,
    const float* __restrict__ bq, const float* __restrict__ bk, const float* __restrict__ bv,
    unsigned short* __restrict__ Qh, unsigned short* __restrict__ Kh,
    unsigned short* __restrict__ Vh, float sc)
{
  __shared__ __align__(16) unsigned short As[2 * 8192];
  __shared__ __align__(16) unsigned short Bs[2 * 8192];
  int z = blockIdx.z;
  const unsigned short* X = (z == 0) ? Xq : (z == 1) ? Xk : Xv;
  const unsigned short* W = (z == 0) ? Wq : (z == 1) ? Wk : Wv;
  const float* bias = (z == 0) ? bq : (z == 1) ? bk : bv;
  void* Y = (z == 0) ? (void*)Qh : (z == 1) ? (void*)Kh : (void*)Vh;
  float scale = (z == 0) ? sc : 1.0f;
  int mode = (z == 2) ? 2 : 0;
  gemm_core(X, W, bias, Y, scale, mode, blockIdx.y, blockIdx.x, As, Bs);
}

__global__ __launch_bounds__(256) void gemm_out(
    const unsigned short* __restrict__ X, const unsigned short* __restrict__ W,
    const float* __restrict__ bias, float* __restrict__ Y)
{
  __shared__ __align__(16) unsigned short As[2 * 8192];
  __shared__ __align__(16) unsigned short Bs[2 * 8192];
  gemm_core(X, W, bias, Y, 1.0f, 1, blockIdx.y, blockIdx.x, As, Bs);
}

// ---------- flash attention: pipelined dbuf LDS K/V tiles, transposed-score softmax ----------
__global__ __launch_bounds__(256) void attn_kernel(
    const unsigned short* __restrict__ Qh,
    const unsigned short* __restrict__ Kh,
    const _Float16* __restrict__ Vt,
    const unsigned long long* __restrict__ mbits,
    unsigned short* __restrict__ attnb)
{
  __shared__ __align__(16) unsigned short Ks[2 * 4096];
  __shared__ __align__(16) unsigned short Vs[2 * 4096];

  int tid = threadIdx.x;
  int wave = tid >> 6, lane = tid & 63, quad = lane >> 4, li = lane & 15;

  int blk = blockIdx.x;
  int xcd = blk & 7, slot7 = blk >> 3;
  int bh = xcd * 8 + (slot7 >> 4);
  int qb = slot7 & 15;
  int b = bh >> 4, h = bh & 15;
  int qbase = qb * 128 + wave * 32;
  const size_t hq = (size_t)bh * S_ * DK_;

  // Q fragments (B-operand of S^T mfma), loaded once from global
  short8 aQ[2][2];
#pragma unroll
  for (int qs = 0; qs < 2; ++qs)
#pragma unroll
    for (int s2 = 0; s2 < 2; ++s2)
      aQ[qs][s2] = *(const short8*)(Qh + hq + (size_t)(qbase + qs * 16 + li) * DK_ + s2 * 32 + quad * 8);

  floatx4 o[2][4] = {};
  float l[2] = {0.f, 0.f};

  const unsigned long long* mrow = mbits + ((size_t)b * S_ + qbase + li) * (S_ / 64);

  // staging: wave w covers rows w*16..w*16+15; call j covers 8 rows
  int srow = lane >> 3;
  int scol = ((lane & 7) ^ srow) * 8;   // XOR swizzle on global side
  const unsigned short* gK = Kh + hq + (size_t)(wave * 16 + srow) * DK_ + scol;
  const _Float16* gV = Vt + ((size_t)bh * 64 + wave * 16 + srow) * S_ + scol;

  auto stage = [&](int buf, int k0) {
#pragma unroll
    for (int j = 0; j < 2; ++j) {
      __builtin_amdgcn_global_load_lds((gvp)(gK + (size_t)(k0 + j * 8) * DK_),
          (lvp)(Ks + buf * 4096 + wave * 1024 + j * 512), 16, 0, 0);
      __builtin_amdgcn_global_load_lds((gvp)(gV + (size_t)(j * 8) * S_ + k0),
          (lvp)(Vs + buf * 4096 + wave * 1024 + j * 512), 16, 0, 0);
    }
  };

  stage(0, 0);
  unsigned long long mw0c = mrow[0];
  unsigned long long mw1c = mrow[16 * (S_ / 64)];

  constexpr int NK = S_ / 64;
  for (int i = 0; i < NK; ++i) {
    int buf = i & 1;
    __syncthreads();                        // buf valid; prev prefetch landed during compute
    if (i + 1 < NK) stage(buf ^ 1, (i + 1) * 64);   // prefetch next K/V tile
    unsigned long long mw0n = 0, mw1n = 0;
    if (i + 1 < NK) { mw0n = mrow[i + 1]; mw1n = mrow[16 * (S_ / 64) + i + 1]; }

    // K fragments from LDS (unswizzle)
    short8 bK[4][2];
#pragma unroll
    for (int t = 0; t < 4; ++t)
#pragma unroll
      for (int s2 = 0; s2 < 2; ++s2)
        bK[t][s2] = *(const short8*)(&Ks[buf * 4096 + (t * 16 + li) * 64 + (((s2 * 4 + quad) ^ (li & 7)) * 8)]);

    // V fragments from LDS (unswizzle)
    V8u vv[4][2];
#pragma unroll
    for (int dt = 0; dt < 4; ++dt)
#pragma unroll
      for (int tp = 0; tp < 2; ++tp)
        vv[dt][tp].v8 = *(const half8*)((const _Float16*)&Vs[buf * 4096 + (dt * 16 + li) * 64 + (((tp * 4 + quad) ^ (li & 7)) * 8)]);

    // scores transposed: lane holds S[q=li][k = i*64 + t*16 + quad*4 + r]
    floatx4 sc[4][2] = {};
#pragma unroll
    for (int s2 = 0; s2 < 2; ++s2)
#pragma unroll
      for (int t = 0; t < 4; ++t)
#pragma unroll
        for (int qs = 0; qs < 2; ++qs)
          sc[t][qs] = __builtin_amdgcn_mfma_f32_16x16x32_bf16(bK[t][s2], aQ[qs][s2], sc[t][qs], 0, 0, 0);

    unsigned long long sh0 = mw0c >> (quad * 4);
    unsigned long long sh1 = mw1c >> (quad * 4);

    // softmax without max-subtraction (exp2-domain scores): P = mask ? exp2(s) : 0
    half4 aP[4][2];
#pragma unroll
    for (int t = 0; t < 4; ++t)
#pragma unroll
      for (int qs = 0; qs < 2; ++qs) {
        unsigned nb = (unsigned)(((qs ? sh1 : sh0) >> (t * 16)) & 15u);
        float p0 = (nb & 1u)        ? exp2f(sc[t][qs][0]) : 0.f;
        float p1 = ((nb >> 1) & 1u) ? exp2f(sc[t][qs][1]) : 0.f;
        float p2 = ((nb >> 2) & 1u) ? exp2f(sc[t][qs][2]) : 0.f;
        float p3 = ((nb >> 3) & 1u) ? exp2f(sc[t][qs][3]) : 0.f;
        l[qs] += (p0 + p1) + (p2 + p3);
        half2_t plo = pk_f16(p0, p1);
        half2_t phi = pk_f16(p2, p3);
        aP[t][qs] = __builtin_shufflevector(plo, phi, 0, 1, 2, 3);
      }

    // PV
#pragma unroll
    for (int t = 0; t < 4; ++t)
#pragma unroll
      for (int qs = 0; qs < 2; ++qs)
#pragma unroll
        for (int dt = 0; dt < 4; ++dt)
          o[qs][dt] = __builtin_amdgcn_mfma_f32_16x16x16f16(aP[t][qs], vv[dt][t >> 1].v4[t & 1], o[qs][dt], 0, 0, 0);

    mw0c = mw0n; mw1c = mw1n;
  }

  float inv[2];
#pragma unroll
  for (int qs = 0; qs < 2; ++qs) {
    float lf = l[qs];
    lf += __shfl_xor(lf, 16, 64);
    lf += __shfl_xor(lf, 32, 64);
    inv[qs] = 1.0f / lf;
  }
#pragma unroll
  for (int qs = 0; qs < 2; ++qs)
#pragma unroll
    for (int r = 0; r < 4; ++r) {
      float ir = __shfl(inv[qs], quad * 4 + r, 64);
      size_t row = (size_t)b * S_ + qbase + qs * 16 + quad * 4 + r;
#pragma unroll
      for (int dt = 0; dt < 4; ++dt)
        attnb[row * D_ + h * DK_ + dt * 16 + li] = f2bf(o[qs][dt][r] * ir);
    }
}

// ---------- host ----------
extern "C" void kernel_launch(void* const* d_in, const int* in_sizes, int n_in,
                              void* d_out, int out_size, void* d_ws, size_t ws_size,
                              hipStream_t stream) {
  const float* query = (const float*)d_in[0];
  const float* key   = (const float*)d_in[1];
  const float* value = (const float*)d_in[2];
  const int*   mask  = (const int*)d_in[3];
  const float* Wq = (const float*)d_in[4];
  const float* bq = (const float*)d_in[5];
  const float* Wk = (const float*)d_in[6];
  const float* bk = (const float*)d_in[7];
  const float* Wv = (const float*)d_in[8];
  const float* bv = (const float*)d_in[9];
  const float* Wo = (const float*)d_in[10];
  const float* bo = (const float*)d_in[11];
  float* out = (float*)d_out;

  char* ws = (char*)d_ws;
  size_t off = 0;
  auto alloc = [&](size_t bytes) -> void* {
    void* p = ws + off;
    off += (bytes + 255) & ~(size_t)255;
    return p;
  };
  unsigned short* Xq    = (unsigned short*)alloc((size_t)BS_ * D_ * 2);
  unsigned short* Xk    = (unsigned short*)alloc((size_t)BS_ * D_ * 2);
  unsigned short* Xv    = (unsigned short*)alloc((size_t)BS_ * D_ * 2);
  unsigned short* Wqb   = (unsigned short*)alloc((size_t)D_ * D_ * 2);
  unsigned short* Wkb   = (unsigned short*)alloc((size_t)D_ * D_ * 2);
  unsigned short* Wvb   = (unsigned short*)alloc((size_t)D_ * D_ * 2);
  unsigned short* Wob   = (unsigned short*)alloc((size_t)D_ * D_ * 2);
  unsigned short* Qh    = (unsigned short*)alloc((size_t)BS_ * D_ * 2);
  unsigned short* Kh    = (unsigned short*)alloc((size_t)BS_ * D_ * 2);
  unsigned short* Vh    = (unsigned short*)alloc((size_t)BS_ * D_ * 2);  // f16 bits
  unsigned short* Vt    = (unsigned short*)alloc((size_t)BS_ * D_ * 2);  // f16 bits
  unsigned short* attnb = (unsigned short*)alloc((size_t)BS_ * D_ * 2);
  unsigned long long* mbits = (unsigned long long*)alloc((size_t)B_ * S_ * (S_ / 64) * 8);

  const float SC = 0.18033688011112042f;  // (1/8) * log2(e), folded into Q

  pack_mask<<<(B_ * S_ * S_) / 256, 256, 0, stream>>>(mask, mbits);

  int wn4 = D_ * D_ / 4;
  cast4_kernel<<<dim3(wn4 / 256, 4), 256, 0, stream>>>(Wq, Wk, Wv, Wo, Wqb, Wkb, Wvb, Wob, wn4);

  int xn4 = BS_ * D_ / 4;
  cast3_kernel<<<dim3(xn4 / 256, 3), 256, 0, stream>>>(query, key, value, Xq, Xk, Xv, xn4);

  gemm_qkv<<<dim3(D_ / 128, BS_ / 128, 3), 256, 0, stream>>>(
      Xq, Xk, Xv, Wqb, Wkb, Wvb, bq, bk, bv, Qh, Kh, Vh, SC);

  transpose_v<<<dim3(S_ / 64, B_ * H_), 256, 0, stream>>>(Vh, Vt);

  attn_kernel<<<dim3(8 * 8 * 16), 256, 0, stream>>>(Qh, Kh, (const _Float16*)Vt, mbits, attnb);

  gemm_out<<<dim3(D_ / 128, BS_ / 128), 256, 0, stream>>>(attnb, Wob, bo, out);
}